// Round 3
// baseline (252.694 us; speedup 1.0000x reference)
//
#include <hip/hip_runtime.h>

#define H_DIM 1024
#define I_DIM 512
#define E_EXP 16
#define BM    128
#define BK    64
#define BSTR  68   // Bs row stride in shorts (64 + 4 pad)

using bf16x8   = __attribute__((ext_vector_type(8))) short;
using floatx4  = __attribute__((ext_vector_type(4))) float;
using ushort4v = __attribute__((ext_vector_type(4))) unsigned short;

__device__ __forceinline__ unsigned short f2bf(float f) {
  union { float f; unsigned u; } v; v.f = f;
  return (unsigned short)((v.u + 0x7FFFu + ((v.u >> 16) & 1u)) >> 16);  // RNE
}
__device__ __forceinline__ unsigned pk2(float a, float b) {
  return (unsigned)f2bf(a) | ((unsigned)f2bf(b) << 16);
}

__device__ __forceinline__ void gld16(const void* g, void* l) {
  __builtin_amdgcn_global_load_lds((const __attribute__((address_space(1))) void*)g,
                                   (__attribute__((address_space(3))) void*)l,
                                   16, 0, 0);
}

// barrier draining LDS ops only (all vmem stays in flight)
__device__ __forceinline__ void bar_lgkm() {
  asm volatile("s_waitcnt lgkmcnt(0)" ::: "memory");
  __builtin_amdgcn_sched_barrier(0);
  __builtin_amdgcn_s_barrier();
  __builtin_amdgcn_sched_barrier(0);
}
// step-end barrier: drain gld16 A-stage (4 oldest), keep 8 B-prefetch loads flying
__device__ __forceinline__ void bar_v8() {
  asm volatile("s_waitcnt vmcnt(8) lgkmcnt(0)" ::: "memory");
  __builtin_amdgcn_sched_barrier(0);
  __builtin_amdgcn_s_barrier();
  __builtin_amdgcn_sched_barrier(0);
}
// final drain
__device__ __forceinline__ void bar_v0() {
  asm volatile("s_waitcnt vmcnt(0) lgkmcnt(0)" ::: "memory");
  __builtin_amdgcn_sched_barrier(0);
  __builtin_amdgcn_s_barrier();
  __builtin_amdgcn_sched_barrier(0);
}

__device__ __forceinline__ bool tile_info(const int* __restrict__ counts, int by,
                                          int& e, int& row0, int& base, int& cnt) {
  int acc = 0, off = 0;
  e = -1;
  #pragma unroll
  for (int i = 0; i < E_EXP; ++i) {
    int c = counts[i];
    int nt = (c + BM - 1) >> 7;
    if (e < 0 && by < acc + nt) { e = i; row0 = (by - acc) * BM; base = off; cnt = c; }
    acc += nt; off += c;
  }
  return e >= 0;
}

// XCD-2D decode: assuming XCD = id % 8 round-robin, XCD r owns x-pair (r&3) and
// y-range 24*(r>>2).. so weight-strip and A-tile re-reads stay in one L2.
__device__ __forceinline__ void xcd2d(int id, int& bx, int& by) {
  int r = id & 7, j = id >> 3;
  bx = ((r & 3) << 1) | (j & 1);     // 0..7
  by = ((r >> 2) * 24) + (j >> 1);   // 0..47
}

// ---------------- x: fp32 -> bf16 (streaming) ----------------
__global__ void k_cvt(const float* __restrict__ x, unsigned short* __restrict__ xb) {
  const float4* s4 = (const float4*)x;
  int b0 = blockIdx.x * 512 + threadIdx.x;
  float4 a = s4[b0];
  float4 b = s4[b0 + 256];
  ushort4v oa, ob;
  oa.x = f2bf(a.x); oa.y = f2bf(a.y); oa.z = f2bf(a.z); oa.w = f2bf(a.w);
  ob.x = f2bf(b.x); ob.y = f2bf(b.y); ob.z = f2bf(b.z); ob.w = f2bf(b.w);
  ((ushort4v*)xb)[b0] = oa;
  ((ushort4v*)xb)[b0 + 256] = ob;
}

// ---------------- GEMM A: h = silu(x@Wg)*(x@Wu) ----------------
// 2-deep B prefetch: loadB(t+2) issued at step t, converted/written at step t+1
// => ~1.5 K-steps of vmem flight. Per step: gldA(t+1)->As[nxt], loadB(t+2)->bvNxt,
// compute(cur), bar_lgkm (Bs readers done, vmem flying), writeB(bvCur)->Bs,
// bar_v8 (drain gldA only). vmcnt never drains to 0 in the loop.
__launch_bounds__(256, 3)
__global__ void k_gemm_a(const unsigned short* __restrict__ xb,
                         const float* __restrict__ wgu,
                         unsigned short* __restrict__ hb,
                         const int* __restrict__ counts) {
  __shared__ unsigned short As[2][BM * BK];   // 32 KB
  __shared__ unsigned short Bs[BM * BSTR];    // 17 KB (single; WAR covered by bar_lgkm)

  int bx, by;
  xcd2d(blockIdx.x, bx, by);
  int e, row0, base, cnt;
  if (!tile_info(counts, by, e, row0, base, cnt)) return;
  const int rows = (cnt - row0 < BM) ? (cnt - row0) : BM;
  const int c0 = bx * 64;

  const int tid = threadIdx.x;
  const int w = tid >> 6, l = tid & 63;
  const int lr = l & 15, q = l >> 4;
  const int asr = l >> 3;                     // A staging: LDS slot row in 8-row group
  const int akc = ((l & 7) ^ asr) * 8;        // XOR-swizzled global 16B chunk (shorts)
  const int cswz = lr & 7;                    // A read-side swizzle key

  // B staging coords: thread owns cols nl4..nl4+3, k rows kb8..kb8+7
  const int nl4 = (tid & 31) * 4;
  const int kb8 = (tid >> 5) * 8;
  const int gc4 = (nl4 < 64) ? (c0 + nl4) : (I_DIM + c0 + nl4 - 64);
  const float* wmat = wgu + (size_t)e * H_DIM * (2 * I_DIM) + gc4;
  unsigned int* BsD = (unsigned int*)Bs;
  const int bd0 = nl4 * (BSTR / 2) + (kb8 >> 1);

  const int mhalf = w & 1, nhalf = w >> 1;
  const int mrow = mhalf * 64;
  const unsigned short* arow = xb + (size_t)(base + row0) * H_DIM;

  int agr[4];
  #pragma unroll
  for (int t = 0; t < 4; ++t) {
    int r = w * 32 + t * 8 + asr;
    agr[t] = (r < rows) ? r : rows - 1;
  }

  floatx4 accg[4][2], accu[4][2];
  #pragma unroll
  for (int i = 0; i < 4; ++i)
    #pragma unroll
    for (int j = 0; j < 2; ++j) { accg[i][j] = (floatx4){0,0,0,0}; accu[i][j] = (floatx4){0,0,0,0}; }

  float4 bvA[8], bvB[8];

  auto loadB = [&](int kk, float4 (&bv)[8]) {
    #pragma unroll
    for (int j = 0; j < 8; ++j)
      bv[j] = *(const float4*)&wmat[(size_t)(kk + kb8 + j) * (2 * I_DIM)];
  };
  auto loadA = [&](int kk, int buf) {
    #pragma unroll
    for (int t = 0; t < 4; ++t)
      gld16(&arow[(size_t)agr[t] * H_DIM + kk + akc], &As[buf][(w * 32 + t * 8) * BK]);
  };
  auto writeB = [&](float4 (&bv)[8]) {
    #pragma unroll
    for (int c = 0; c < 4; ++c) {
      uint2 d0, d1;
      d0.x = pk2(bv[0][c], bv[1][c]); d0.y = pk2(bv[2][c], bv[3][c]);
      d1.x = pk2(bv[4][c], bv[5][c]); d1.y = pk2(bv[6][c], bv[7][c]);
      *(uint2*)&BsD[bd0 + c * (BSTR / 2)]     = d0;
      *(uint2*)&BsD[bd0 + c * (BSTR / 2) + 2] = d1;
    }
  };
  auto compute = [&](int cb) {
    #pragma unroll
    for (int kf = 0; kf < 2; ++kf) {
      const int c = kf * 4 + q;
      const int ca = (c ^ cswz) * 8;          // swizzled A chunk
      const int ch = c * 8;                   // linear B chunk
      bf16x8 af[4], bg[2], bu[2];
      #pragma unroll
      for (int mi = 0; mi < 4; ++mi)
        af[mi] = *(const bf16x8*)&As[cb][(mrow + mi * 16 + lr) * BK + ca];
      #pragma unroll
      for (int ni = 0; ni < 2; ++ni) {
        bg[ni] = *(const bf16x8*)&Bs[(nhalf * 32 + ni * 16 + lr) * BSTR + ch];
        bu[ni] = *(const bf16x8*)&Bs[(64 + nhalf * 32 + ni * 16 + lr) * BSTR + ch];
      }
      #pragma unroll
      for (int mi = 0; mi < 4; ++mi)
        #pragma unroll
        for (int ni = 0; ni < 2; ++ni) {
          accg[mi][ni] = __builtin_amdgcn_mfma_f32_16x16x32_bf16(af[mi], bg[ni], accg[mi][ni], 0, 0, 0);
          accu[mi][ni] = __builtin_amdgcn_mfma_f32_16x16x32_bf16(af[mi], bu[ni], accu[mi][ni], 0, 0, 0);
        }
    }
  };

  // ---- prologue: tiles 0 and 1 in flight ----
  loadB(0, bvA);            // 8 loads (oldest)
  loadA(0, 0);              // 4 gld16
  loadB(BK, bvB);           // 8 loads (newest)
  writeB(bvA);              // auto-waits vmcnt(12): bvA done, rest flying
  bar_v8();                 // drain gldA(0); bvB(8) stays in flight
  int cur = 0;              // bvB holds tile 1 fp32

  // ---- main loop: 14 steps, unrolled x2 for static bv roles ----
  #pragma unroll 1
  for (int i = 0; i < 7; ++i) {
    const int t = 2 * i;
    // even step: compute tile t; bvCur=bvB (tile t+1), load tile t+2 -> bvA
    loadA((t + 1) * BK, cur ^ 1);
    loadB((t + 2) * BK, bvA);
    __builtin_amdgcn_sched_barrier(0);
    compute(cur);
    bar_lgkm();
    writeB(bvB);
    bar_v8();
    cur ^= 1;
    // odd step: compute tile t+1; bvCur=bvA (tile t+2), load tile t+3 -> bvB
    loadA((t + 2) * BK, cur ^ 1);
    loadB((t + 3) * BK, bvB);
    __builtin_amdgcn_sched_barrier(0);
    compute(cur);
    bar_lgkm();
    writeB(bvA);
    bar_v8();
    cur ^= 1;
  }
  // ---- step 14: no more B loads; bvB holds tile 15 ----
  loadA(15 * BK, cur ^ 1);
  __builtin_amdgcn_sched_barrier(0);
  compute(cur);             // tile 14
  bar_lgkm();
  writeB(bvB);              // tile 15
  bar_v0();
  cur ^= 1;
  compute(cur);             // tile 15

  #pragma unroll
  for (int mi = 0; mi < 4; ++mi)
    #pragma unroll
    for (int r = 0; r < 4; ++r) {
      int row_local = mrow + mi * 16 + q * 4 + r;
      if (row_local >= rows) continue;
      size_t orow = (size_t)(base + row0 + row_local) * I_DIM;
      #pragma unroll
      for (int ni = 0; ni < 2; ++ni) {
        float g = accg[mi][ni][r], u = accu[mi][ni][r];
        float s = g / (1.0f + __expf(-g)) * u;
        hb[orow + c0 + nhalf * 32 + ni * 16 + lr] = f2bf(s);
      }
    }
}

// ---------------- GEMM B: out = h @ Wd (same pipeline) ----------------
__launch_bounds__(256, 3)
__global__ void k_gemm_b(const unsigned short* __restrict__ hb,
                         const float* __restrict__ wdn,
                         float* __restrict__ out,
                         const int* __restrict__ counts) {
  __shared__ unsigned short As[2][BM * BK];
  __shared__ unsigned short Bs[BM * BSTR];

  int bx, by;
  xcd2d(blockIdx.x, bx, by);
  int e, row0, base, cnt;
  if (!tile_info(counts, by, e, row0, base, cnt)) return;
  const int rows = (cnt - row0 < BM) ? (cnt - row0) : BM;
  const int n0 = bx * 128;

  const int tid = threadIdx.x;
  const int w = tid >> 6, l = tid & 63;
  const int lr = l & 15, q = l >> 4;
  const int asr = l >> 3;
  const int akc = ((l & 7) ^ asr) * 8;
  const int cswz = lr & 7;

  const int nl4 = (tid & 31) * 4;
  const int kb8 = (tid >> 5) * 8;
  const float* wmat = wdn + (size_t)e * I_DIM * H_DIM + n0 + nl4;
  unsigned int* BsD = (unsigned int*)Bs;
  const int bd0 = nl4 * (BSTR / 2) + (kb8 >> 1);

  const int mhalf = w & 1, nhalf = w >> 1;
  const int mrow = mhalf * 64;
  const unsigned short* arow = hb + (size_t)(base + row0) * I_DIM;

  int agr[4];
  #pragma unroll
  for (int t = 0; t < 4; ++t) {
    int r = w * 32 + t * 8 + asr;
    agr[t] = (r < rows) ? r : rows - 1;
  }

  floatx4 acc[4][4];
  #pragma unroll
  for (int i = 0; i < 4; ++i)
    #pragma unroll
    for (int j = 0; j < 4; ++j) acc[i][j] = (floatx4){0,0,0,0};

  float4 bvA[8], bvB[8];

  auto loadB = [&](int kk, float4 (&bv)[8]) {
    #pragma unroll
    for (int j = 0; j < 8; ++j)
      bv[j] = *(const float4*)&wmat[(size_t)(kk + kb8 + j) * H_DIM];
  };
  auto loadA = [&](int kk, int buf) {
    #pragma unroll
    for (int t = 0; t < 4; ++t)
      gld16(&arow[(size_t)agr[t] * I_DIM + kk + akc], &As[buf][(w * 32 + t * 8) * BK]);
  };
  auto writeB = [&](float4 (&bv)[8]) {
    #pragma unroll
    for (int c = 0; c < 4; ++c) {
      uint2 d0, d1;
      d0.x = pk2(bv[0][c], bv[1][c]); d0.y = pk2(bv[2][c], bv[3][c]);
      d1.x = pk2(bv[4][c], bv[5][c]); d1.y = pk2(bv[6][c], bv[7][c]);
      *(uint2*)&BsD[bd0 + c * (BSTR / 2)]     = d0;
      *(uint2*)&BsD[bd0 + c * (BSTR / 2) + 2] = d1;
    }
  };
  auto compute = [&](int cb) {
    #pragma unroll
    for (int kf = 0; kf < 2; ++kf) {
      const int c = kf * 4 + q;
      const int ca = (c ^ cswz) * 8;
      const int ch = c * 8;
      bf16x8 af[4], bf[4];
      #pragma unroll
      for (int mi = 0; mi < 4; ++mi)
        af[mi] = *(const bf16x8*)&As[cb][(mrow + mi * 16 + lr) * BK + ca];
      #pragma unroll
      for (int ni = 0; ni < 4; ++ni)
        bf[ni] = *(const bf16x8*)&Bs[(nhalf * 64 + ni * 16 + lr) * BSTR + ch];
      #pragma unroll
      for (int mi = 0; mi < 4; ++mi)
        #pragma unroll
        for (int ni = 0; ni < 4; ++ni)
          acc[mi][ni] = __builtin_amdgcn_mfma_f32_16x16x32_bf16(af[mi], bf[ni], acc[mi][ni], 0, 0, 0);
    }
  };

  // prologue: tiles 0,1
  loadB(0, bvA);
  loadA(0, 0);
  loadB(BK, bvB);
  writeB(bvA);
  bar_v8();
  int cur = 0;

  // main loop: nk=8 -> 6 steps = 3 x 2
  #pragma unroll 1
  for (int i = 0; i < 3; ++i) {
    const int t = 2 * i;
    loadA((t + 1) * BK, cur ^ 1);
    loadB((t + 2) * BK, bvA);
    __builtin_amdgcn_sched_barrier(0);
    compute(cur);
    bar_lgkm();
    writeB(bvB);
    bar_v8();
    cur ^= 1;
    loadA((t + 2) * BK, cur ^ 1);
    loadB((t + 3) * BK, bvB);
    __builtin_amdgcn_sched_barrier(0);
    compute(cur);
    bar_lgkm();
    writeB(bvA);
    bar_v8();
    cur ^= 1;
  }
  // step 6: bvB holds tile 7
  loadA(7 * BK, cur ^ 1);
  __builtin_amdgcn_sched_barrier(0);
  compute(cur);             // tile 6
  bar_lgkm();
  writeB(bvB);              // tile 7
  bar_v0();
  cur ^= 1;
  compute(cur);             // tile 7

  #pragma unroll
  for (int mi = 0; mi < 4; ++mi)
    #pragma unroll
    for (int r = 0; r < 4; ++r) {
      int row_local = mrow + mi * 16 + q * 4 + r;
      if (row_local >= rows) continue;
      size_t orow = (size_t)(base + row0 + row_local) * H_DIM;
      #pragma unroll
      for (int ni = 0; ni < 4; ++ni)
        out[orow + n0 + nhalf * 64 + ni * 16 + lr] = acc[mi][ni][r];
    }
}

// ---------------- launch ----------------
extern "C" void kernel_launch(void* const* d_in, const int* in_sizes, int n_in,
                              void* d_out, int out_size, void* d_ws, size_t ws_size,
                              hipStream_t stream) {
  const float* x      = (const float*)d_in[0];
  const float* wgu    = (const float*)d_in[1];
  const float* wdn    = (const float*)d_in[2];
  const int*   counts = (const int*)d_in[3];
  float* out = (float*)d_out;

  unsigned char* ws = (unsigned char*)d_ws;
  unsigned short* xb = (unsigned short*)(ws);            // 8 MB
  unsigned short* hb = (unsigned short*)(ws + 8388608);  // 4 MB

  k_cvt<<<2048, 256, 0, stream>>>(x, xb);
  k_gemm_a<<<384, 256, 0, stream>>>(xb, wgu, hb, counts);   // 8 x-blocks x 48 y-tiles, XCD-2D decoded
  k_gemm_b<<<384, 256, 0, stream>>>(hb, wdn, out, counts);  // 8 x-blocks x 48 y-tiles
}

// Round 4
// 170.287 us; speedup vs baseline: 1.4839x; 1.4839x over previous
//
#include <hip/hip_runtime.h>

#define H_DIM 1024
#define I_DIM 512
#define E_EXP 16
#define BM    128
#define BK    64
#define BSTR  68   // Bs row stride in shorts (64 + 4 pad)

using bf16x8   = __attribute__((ext_vector_type(8))) short;
using floatx4  = __attribute__((ext_vector_type(4))) float;
using ushort4v = __attribute__((ext_vector_type(4))) unsigned short;

__device__ __forceinline__ unsigned short f2bf(float f) {
  union { float f; unsigned u; } v; v.f = f;
  return (unsigned short)((v.u + 0x7FFFu + ((v.u >> 16) & 1u)) >> 16);  // RNE
}
__device__ __forceinline__ unsigned pk2(float a, float b) {
  return (unsigned)f2bf(a) | ((unsigned)f2bf(b) << 16);
}

__device__ __forceinline__ void gld16(const void* g, void* l) {
  __builtin_amdgcn_global_load_lds((const __attribute__((address_space(1))) void*)g,
                                   (__attribute__((address_space(3))) void*)l,
                                   16, 0, 0);
}

// barrier draining LDS ops only (vmem prefetch stays in flight)
__device__ __forceinline__ void bar_lgkm() {
  asm volatile("s_waitcnt lgkmcnt(0)" ::: "memory");
  __builtin_amdgcn_sched_barrier(0);
  __builtin_amdgcn_s_barrier();
  __builtin_amdgcn_sched_barrier(0);
}
// full drain (gld16 A-stage + remaining vmem) — once per K-step
__device__ __forceinline__ void bar_full() {
  asm volatile("s_waitcnt vmcnt(0) lgkmcnt(0)" ::: "memory");
  __builtin_amdgcn_sched_barrier(0);
  __builtin_amdgcn_s_barrier();
  __builtin_amdgcn_sched_barrier(0);
}

__device__ __forceinline__ bool tile_info(const int* __restrict__ counts, int by,
                                          int& e, int& row0, int& base, int& cnt) {
  int acc = 0, off = 0;
  e = -1;
  #pragma unroll
  for (int i = 0; i < E_EXP; ++i) {
    int c = counts[i];
    int nt = (c + BM - 1) >> 7;
    if (e < 0 && by < acc + nt) { e = i; row0 = (by - acc) * BM; base = off; cnt = c; }
    acc += nt; off += c;
  }
  return e >= 0;
}

// ---------------- x: fp32 -> bf16 (streaming) ----------------
__global__ void k_cvt(const float* __restrict__ x, unsigned short* __restrict__ xb) {
  const float4* s4 = (const float4*)x;
  int b0 = blockIdx.x * 512 + threadIdx.x;
  float4 a = s4[b0];
  float4 b = s4[b0 + 256];
  ushort4v oa, ob;
  oa.x = f2bf(a.x); oa.y = f2bf(a.y); oa.z = f2bf(a.z); oa.w = f2bf(a.w);
  ob.x = f2bf(b.x); ob.y = f2bf(b.y); ob.z = f2bf(b.z); ob.w = f2bf(b.w);
  ((ushort4v*)xb)[b0] = oa;
  ((ushort4v*)xb)[b0 + 256] = ob;
}

// ---------------- GEMM A: h = silu(x@Wg)*(x@Wu) ----------------
// 32-col tiles -> grid (16,48) = 768 blocks = 3/CU (12 waves/CU): TLP hides
// the staging latency (m114). Per-thread B staging is 4 x float4 (16 VGPR,
// cannot spill). Round-2 pipeline: issue B(t+1)+A(t+1) -> compute(t) ->
// bar_lgkm -> convert+write Bs -> bar_full.
__launch_bounds__(256, 3)
__global__ void k_gemm_a(const unsigned short* __restrict__ xb,
                         const float* __restrict__ wgu,
                         unsigned short* __restrict__ hb,
                         const int* __restrict__ counts) {
  __shared__ unsigned short As[2][BM * BK];   // 32 KB
  __shared__ unsigned short Bs[64 * BSTR];    // 8.7 KB; rows 0-31 g, 32-63 u

  int e, row0, base, cnt;
  if (!tile_info(counts, blockIdx.y, e, row0, base, cnt)) return;
  const int rows = (cnt - row0 < BM) ? (cnt - row0) : BM;
  const int c0 = blockIdx.x * 32;

  const int tid = threadIdx.x;
  const int w = tid >> 6, l = tid & 63;
  const int lr = l & 15, q = l >> 4;
  const int asr = l >> 3;                     // A staging: LDS slot row in 8-row group
  const int akc = ((l & 7) ^ asr) * 8;        // XOR-swizzled global 16B chunk (shorts)
  const int cswz = lr & 7;                    // A read-side swizzle key

  // B staging: thread owns 4 cols (chunk f4) of g-or-u (seg), k rows kb..kb+3
  const int f4  = tid & 7;                    // 4-col chunk within 32
  const int seg = (tid >> 3) & 1;             // 0 = gate, 1 = up
  const int kb  = (tid >> 4) * 4;             // 0..60
  const float* gptr = wgu + (size_t)e * H_DIM * (2 * I_DIM) + c0 + f4 * 4 + seg * I_DIM;
  unsigned int* BsD = (unsigned int*)Bs;

  const int mhalf = w & 1, nhalf = w >> 1;
  const int mrow = mhalf * 64;
  const unsigned short* arow = xb + (size_t)(base + row0) * H_DIM;

  int agr[4];
  #pragma unroll
  for (int t = 0; t < 4; ++t) {
    int r = w * 32 + t * 8 + asr;
    agr[t] = (r < rows) ? r : rows - 1;
  }

  floatx4 accg[4], accu[4];
  #pragma unroll
  for (int i = 0; i < 4; ++i) { accg[i] = (floatx4){0,0,0,0}; accu[i] = (floatx4){0,0,0,0}; }

  float4 bv[4];

  auto loadB = [&](int kk) {
    #pragma unroll
    for (int j = 0; j < 4; ++j)
      bv[j] = *(const float4*)&gptr[(size_t)(kk + kb + j) * (2 * I_DIM)];
  };
  auto loadA = [&](int kk, int buf) {
    #pragma unroll
    for (int t = 0; t < 4; ++t)
      gld16(&arow[(size_t)agr[t] * H_DIM + kk + akc], &As[buf][(w * 32 + t * 8) * BK]);
  };
  auto writeB = [&]() {
    #pragma unroll
    for (int c = 0; c < 4; ++c) {
      uint2 d;
      d.x = pk2(bv[0][c], bv[1][c]);
      d.y = pk2(bv[2][c], bv[3][c]);
      *(uint2*)&BsD[(seg * 32 + f4 * 4 + c) * (BSTR / 2) + (kb >> 1)] = d;
    }
  };
  auto compute = [&](int cb) {
    #pragma unroll
    for (int kf = 0; kf < 2; ++kf) {
      const int c = kf * 4 + q;
      const int ca = (c ^ cswz) * 8;          // swizzled A chunk
      const int ch = c * 8;                   // linear B chunk
      bf16x8 af[4], bg, bu;
      #pragma unroll
      for (int mi = 0; mi < 4; ++mi)
        af[mi] = *(const bf16x8*)&As[cb][(mrow + mi * 16 + lr) * BK + ca];
      bg = *(const bf16x8*)&Bs[(nhalf * 16 + lr) * BSTR + ch];
      bu = *(const bf16x8*)&Bs[(32 + nhalf * 16 + lr) * BSTR + ch];
      #pragma unroll
      for (int mi = 0; mi < 4; ++mi) {
        accg[mi] = __builtin_amdgcn_mfma_f32_16x16x32_bf16(af[mi], bg, accg[mi], 0, 0, 0);
        accu[mi] = __builtin_amdgcn_mfma_f32_16x16x32_bf16(af[mi], bu, accu[mi], 0, 0, 0);
      }
    }
  };

  // prologue: stage tile 0
  loadB(0);
  loadA(0, 0);
  writeB();
  __syncthreads();

  const int nk = H_DIM / BK;   // 16
  int cur = 0;
  for (int ki = 0; ki < nk - 1; ++ki) {
    const int kk = (ki + 1) * BK;
    loadB(kk);                  // 4 coalesced float4 loads
    loadA(kk, cur ^ 1);         // 4 gld16 -> other buffer
    __builtin_amdgcn_sched_barrier(0);
    compute(cur);
    bar_lgkm();                 // Bs readers done; prefetch still flying
    writeB();                   // counted vmcnt wait for bv only
    bar_full();
    cur ^= 1;
  }
  compute(cur);                 // tail

  #pragma unroll
  for (int mi = 0; mi < 4; ++mi)
    #pragma unroll
    for (int r = 0; r < 4; ++r) {
      int row_local = mrow + mi * 16 + q * 4 + r;
      if (row_local >= rows) continue;
      size_t orow = (size_t)(base + row0 + row_local) * I_DIM;
      float g = accg[mi][r], u = accu[mi][r];
      float s = g / (1.0f + __expf(-g)) * u;
      hb[orow + c0 + nhalf * 16 + lr] = f2bf(s);
    }
}

// ---------------- GEMM B: out = h @ Wd ----------------
// 64-col tiles -> grid (16,48) = 768 blocks = 3/CU.
__launch_bounds__(256, 3)
__global__ void k_gemm_b(const unsigned short* __restrict__ hb,
                         const float* __restrict__ wdn,
                         float* __restrict__ out,
                         const int* __restrict__ counts) {
  __shared__ unsigned short As[2][BM * BK];
  __shared__ unsigned short Bs[64 * BSTR];

  int e, row0, base, cnt;
  if (!tile_info(counts, blockIdx.y, e, row0, base, cnt)) return;
  const int rows = (cnt - row0 < BM) ? (cnt - row0) : BM;
  const int n0 = blockIdx.x * 64;

  const int tid = threadIdx.x;
  const int w = tid >> 6, l = tid & 63;
  const int lr = l & 15, q = l >> 4;
  const int asr = l >> 3;
  const int akc = ((l & 7) ^ asr) * 8;
  const int cswz = lr & 7;

  const int f4 = tid & 15;                    // 4-col chunk within 64
  const int kb = (tid >> 4) * 4;              // 0..60
  const float* gptr = wdn + (size_t)e * I_DIM * H_DIM + n0 + f4 * 4;
  unsigned int* BsD = (unsigned int*)Bs;

  const int mhalf = w & 1, nhalf = w >> 1;
  const int mrow = mhalf * 64;
  const unsigned short* arow = hb + (size_t)(base + row0) * I_DIM;

  int agr[4];
  #pragma unroll
  for (int t = 0; t < 4; ++t) {
    int r = w * 32 + t * 8 + asr;
    agr[t] = (r < rows) ? r : rows - 1;
  }

  floatx4 acc[4][2];
  #pragma unroll
  for (int i = 0; i < 4; ++i)
    #pragma unroll
    for (int j = 0; j < 2; ++j) acc[i][j] = (floatx4){0,0,0,0};

  float4 bv[4];

  auto loadB = [&](int kk) {
    #pragma unroll
    for (int j = 0; j < 4; ++j)
      bv[j] = *(const float4*)&gptr[(size_t)(kk + kb + j) * H_DIM];
  };
  auto loadA = [&](int kk, int buf) {
    #pragma unroll
    for (int t = 0; t < 4; ++t)
      gld16(&arow[(size_t)agr[t] * I_DIM + kk + akc], &As[buf][(w * 32 + t * 8) * BK]);
  };
  auto writeB = [&]() {
    #pragma unroll
    for (int c = 0; c < 4; ++c) {
      uint2 d;
      d.x = pk2(bv[0][c], bv[1][c]);
      d.y = pk2(bv[2][c], bv[3][c]);
      *(uint2*)&BsD[(f4 * 4 + c) * (BSTR / 2) + (kb >> 1)] = d;
    }
  };
  auto compute = [&](int cb) {
    #pragma unroll
    for (int kf = 0; kf < 2; ++kf) {
      const int c = kf * 4 + q;
      const int ca = (c ^ cswz) * 8;
      const int ch = c * 8;
      bf16x8 af[4], bf[2];
      #pragma unroll
      for (int mi = 0; mi < 4; ++mi)
        af[mi] = *(const bf16x8*)&As[cb][(mrow + mi * 16 + lr) * BK + ca];
      #pragma unroll
      for (int ni = 0; ni < 2; ++ni)
        bf[ni] = *(const bf16x8*)&Bs[(nhalf * 32 + ni * 16 + lr) * BSTR + ch];
      #pragma unroll
      for (int mi = 0; mi < 4; ++mi)
        #pragma unroll
        for (int ni = 0; ni < 2; ++ni)
          acc[mi][ni] = __builtin_amdgcn_mfma_f32_16x16x32_bf16(af[mi], bf[ni], acc[mi][ni], 0, 0, 0);
    }
  };

  loadB(0);
  loadA(0, 0);
  writeB();
  __syncthreads();

  const int nk = I_DIM / BK;   // 8
  int cur = 0;
  for (int ki = 0; ki < nk - 1; ++ki) {
    const int kk = (ki + 1) * BK;
    loadB(kk);
    loadA(kk, cur ^ 1);
    __builtin_amdgcn_sched_barrier(0);
    compute(cur);
    bar_lgkm();
    writeB();
    bar_full();
    cur ^= 1;
  }
  compute(cur);

  #pragma unroll
  for (int mi = 0; mi < 4; ++mi)
    #pragma unroll
    for (int r = 0; r < 4; ++r) {
      int row_local = mrow + mi * 16 + q * 4 + r;
      if (row_local >= rows) continue;
      size_t orow = (size_t)(base + row0 + row_local) * H_DIM;
      #pragma unroll
      for (int ni = 0; ni < 2; ++ni)
        out[orow + n0 + nhalf * 32 + ni * 16 + lr] = acc[mi][ni][r];
    }
}

// ---------------- launch ----------------
extern "C" void kernel_launch(void* const* d_in, const int* in_sizes, int n_in,
                              void* d_out, int out_size, void* d_ws, size_t ws_size,
                              hipStream_t stream) {
  const float* x      = (const float*)d_in[0];
  const float* wgu    = (const float*)d_in[1];
  const float* wdn    = (const float*)d_in[2];
  const int*   counts = (const int*)d_in[3];
  float* out = (float*)d_out;

  unsigned char* ws = (unsigned char*)d_ws;
  unsigned short* xb = (unsigned short*)(ws);            // 8 MB
  unsigned short* hb = (unsigned short*)(ws + 8388608);  // 4 MB

  k_cvt<<<2048, 256, 0, stream>>>(x, xb);
  k_gemm_a<<<dim3(I_DIM / 32, 48), 256, 0, stream>>>(xb, wgu, hb, counts);   // 768 blocks
  k_gemm_b<<<dim3(H_DIM / 64, 48), 256, 0, stream>>>(hb, wdn, out, counts);  // 768 blocks
}